// Round 3
// baseline (16441.800 us; speedup 1.0000x reference)
//
#include <hip/hip_runtime.h>

typedef unsigned short ushort_t;
typedef short sh8 __attribute__((ext_vector_type(8)));     // 8 bf16 (4 VGPR)
typedef float f32x4 __attribute__((ext_vector_type(4)));   // 4 fp32 acc

#define MFMA16(a,b,c) __builtin_amdgcn_mfma_f32_16x16x32_bf16((a),(b),(c),0,0,0)

#define SEQL   512
#define BATCH  64
#define HDIM   1024
#define G3     3072
#define AROWS  (SEQL*BATCH)          // 32768
#define YSZ    (SEQL*BATCH*HDIM)     // 33554432
#define BH     (BATCH*HDIM)          // 65536

__device__ __forceinline__ ushort_t f2bf(float x) {
  unsigned u = __float_as_uint(x);
  u += 0x7FFFu + ((u >> 16) & 1u);    // RNE
  return (ushort_t)(u >> 16);
}
__device__ __forceinline__ float bf2f(ushort_t h) {
  return __uint_as_float(((unsigned)h) << 16);
}

// ---------------- conversion / init ----------------
__global__ void cvt_kernel(const float* __restrict__ wih, const float* __restrict__ whh,
                           const float* __restrict__ h0,
                           ushort_t* __restrict__ WihH, ushort_t* __restrict__ WihL,
                           ushort_t* __restrict__ WhhH, ushort_t* __restrict__ WhhL,
                           ushort_t* __restrict__ hH, ushort_t* __restrict__ hL) {
  const int NW = G3 * HDIM;
  int i0 = blockIdx.x * blockDim.x + threadIdx.x;
  int stride = gridDim.x * blockDim.x;
  for (int i = i0; i < NW; i += stride) {
    float x = wih[i]; ushort_t h = f2bf(x);
    WihH[i] = h; WihL[i] = f2bf(x - bf2f(h));
    float y = whh[i]; ushort_t g = f2bf(y);
    WhhH[i] = g; WhhL[i] = f2bf(y - bf2f(g));
  }
  for (int i = i0; i < BH; i += stride) {
    float x = h0[i];
    ushort_t h = f2bf(x); hH[i] = h; hL[i] = f2bf(x - bf2f(h));
  }
}

// ---------------- phase 1: gx = input @ W_ih^T + b_ih (3-term bf16) ----------------
__global__ __launch_bounds__(256) void gemm_gx(
    const float* __restrict__ A,            // [32768][1024] fp32
    const ushort_t* __restrict__ BHp, const ushort_t* __restrict__ BLp, // [3072][1024]
    const float* __restrict__ bias,         // [3072]
    float* __restrict__ gx)                 // [32768][3072]
{
  int bid = blockIdx.x;
  int mt = bid / 24, nt = bid % 24;
  int w = threadIdx.x >> 6, l = threadIdx.x & 63;
  int lr = l & 15, lk = (l >> 4) * 8;

  f32x4 acc[2][8];
  #pragma unroll
  for (int mi = 0; mi < 2; ++mi)
    #pragma unroll
    for (int ni = 0; ni < 8; ++ni) acc[mi][ni] = (f32x4){0.f, 0.f, 0.f, 0.f};

  int arow0 = mt * 128 + w * 32 + lr;
  int brow0 = nt * 128 + lr;

  for (int k0 = 0; k0 < HDIM; k0 += 32) {
    int ka = k0 + lk;
    sh8 aH[2], aL[2];
    #pragma unroll
    for (int mi = 0; mi < 2; ++mi) {
      const float* ap = A + (size_t)(arow0 + mi * 16) * HDIM + ka;
      float4 x0 = *(const float4*)ap;
      float4 x1 = *(const float4*)(ap + 4);
      float xs[8] = {x0.x, x0.y, x0.z, x0.w, x1.x, x1.y, x1.z, x1.w};
      #pragma unroll
      for (int j = 0; j < 8; ++j) {
        ushort_t h = f2bf(xs[j]);
        aH[mi][j] = (short)h;
        aL[mi][j] = (short)f2bf(xs[j] - bf2f(h));
      }
    }
    #pragma unroll
    for (int ni = 0; ni < 8; ++ni) {
      const ushort_t* bh = BHp + (size_t)(brow0 + ni * 16) * HDIM + ka;
      const ushort_t* bl = BLp + (size_t)(brow0 + ni * 16) * HDIM + ka;
      sh8 bHf = *(const sh8*)bh;
      sh8 bLf = *(const sh8*)bl;
      #pragma unroll
      for (int mi = 0; mi < 2; ++mi) {
        acc[mi][ni] = MFMA16(aH[mi], bHf, acc[mi][ni]);
        acc[mi][ni] = MFMA16(aH[mi], bLf, acc[mi][ni]);
        acc[mi][ni] = MFMA16(aL[mi], bHf, acc[mi][ni]);
      }
    }
  }
  int rb = (l >> 4) * 4;
  #pragma unroll
  for (int mi = 0; mi < 2; ++mi)
    #pragma unroll
    for (int ni = 0; ni < 8; ++ni) {
      int col = nt * 128 + ni * 16 + lr;
      float b = bias[col];
      #pragma unroll
      for (int j = 0; j < 4; ++j) {
        int row = mt * 128 + w * 32 + mi * 16 + rb + j;
        __builtin_nontemporal_store(acc[mi][ni][j] + b, &gx[(size_t)row * G3 + col]);
      }
    }
}

// ---------------- device-scope barrier (relaxed spin, single acquire) ----------------
__device__ __forceinline__ void gbar(unsigned* cnt, unsigned target) {
  __syncthreads();
  if (threadIdx.x == 0) {
    __hip_atomic_fetch_add(cnt, 1u, __ATOMIC_RELEASE, __HIP_MEMORY_SCOPE_AGENT);
    while (__hip_atomic_load(cnt, __ATOMIC_RELAXED, __HIP_MEMORY_SCOPE_AGENT) < target)
      __builtin_amdgcn_s_sleep(1);
    (void)__hip_atomic_load(cnt, __ATOMIC_ACQUIRE, __HIP_MEMORY_SCOPE_AGENT);
  }
  __syncthreads();
}

// load chunk of 8 k-iters of A (hi+lo) into register buffers (static indices)
#define LOADA(BH_, BL_, pH_, pL_, base_) \
  _Pragma("unroll") for (int ii = 0; ii < 8; ++ii) { \
    BH_[ii] = *(const sh8*)(pH_ + ((base_) + ii) * 32); \
    BL_[ii] = *(const sh8*)(pL_ + ((base_) + ii) * 32); }

#define MFRZ(BH_, BL_, base_) \
  _Pragma("unroll") for (int ii = 0; ii < 8; ++ii) { \
    int byt = ((lr << 11) + ((((base_) + ii) * 32 + lk) << 1)) ^ ((lr & 7) << 4); \
    sh8 rW = *(const sh8*)(lds + byt); \
    sh8 zW = *(const sh8*)(lds + 32768 + byt); \
    accR = MFMA16(BH_[ii], rW, accR); \
    accR = MFMA16(BL_[ii], rW, accR); \
    accZ = MFMA16(BH_[ii], zW, accZ); \
    accZ = MFMA16(BL_[ii], zW, accZ); }

#define MFN(BH_, BL_, base_) \
  _Pragma("unroll") for (int ii = 0; ii < 8; ++ii) { \
    int byt = ((lr << 11) + ((((base_) + ii) * 32 + lk) << 1)) ^ ((lr & 7) << 4); \
    sh8 nW = *(const sh8*)(lds + 65536 + byt); \
    sh8 nLo = *(const sh8*)(lds + 98304 + byt); \
    accN = MFMA16(BH_[ii], nW, accN); \
    accN = MFMA16(BH_[ii], nLo, accN); \
    accN = MFMA16(BL_[ii], nW, accN); }

// ---------------- phase 2: persistent recurrence ----------------
// 64 WGs x 256 threads. WG g owns hidden cols [16g,16g+16). Wave w owns rows [16w,16w+16).
// W_hh slices live in LDS (128KB): rH@0, zH@32K, nH@64K, nL@96K, XOR-swizzled.
__global__ __launch_bounds__(256, 1) void gru_rec(
    const float* __restrict__ gx,                 // [512][64][3072]
    const ushort_t* __restrict__ WhhH, const ushort_t* __restrict__ WhhL, // [3072][1024]
    const float* __restrict__ bias_hh,            // [3072]
    ushort_t* __restrict__ hH, ushort_t* __restrict__ hL,   // [2][64][1024]
    ushort_t* __restrict__ rhH, ushort_t* __restrict__ rhL, // [64][1024]
    float* __restrict__ Y, float* __restrict__ Yh,
    unsigned* __restrict__ cnt)
{
  extern __shared__ char lds[];
  const int g = blockIdx.x;
  const int w = threadIdx.x >> 6, l = threadIdx.x & 63;
  const int lr = l & 15, lk = (l >> 4) * 8, rb = (l >> 4) * 4;
  const int c0 = g * 16, m0 = w * 16;
  const int c = c0 + lr;

  // ---- one-time LDS fill: 64 rows x 2KB, swizzled byte ^= (row&7)<<4 ----
  #pragma unroll
  for (int p = 0; p < 32; ++p) {
    int q = threadIdx.x + p * 256;
    int flat = q * 16;
    int lrow = flat >> 11;
    int off = flat & 2047;
    int dst = flat ^ ((lrow & 7) << 4);
    const ushort_t* src;
    if (lrow < 16)      src = WhhH + (size_t)(c0 + lrow) * HDIM;
    else if (lrow < 32) src = WhhH + (size_t)(1024 + c0 + lrow - 16) * HDIM;
    else if (lrow < 48) src = WhhH + (size_t)(2048 + c0 + lrow - 32) * HDIM;
    else                src = WhhL + (size_t)(2048 + c0 + lrow - 48) * HDIM;
    *(sh8*)(lds + dst) = *(const sh8*)(src + (off >> 1));
  }
  __syncthreads();

  const float br = bias_hh[c], bz = bias_hh[1024 + c], bn = bias_hh[2048 + c];
  unsigned bar = 0;

  // prefetch gx r,z for t=0
  float gxr[4], gxz[4], gxn[4];
  #pragma unroll
  for (int j = 0; j < 4; ++j) {
    int b = m0 + rb + j;
    gxr[j] = __builtin_nontemporal_load(gx + (size_t)b * G3 + c);
    gxz[j] = __builtin_nontemporal_load(gx + (size_t)b * G3 + 1024 + c);
  }

  for (int t = 0; t < SEQL; ++t) {
    const int par = t & 1;
    const float* gxt = gx + (size_t)t * (BATCH * G3);

    // ---- stage 1: issue gx_n + own-h loads, then pipelined r,z GEMM ----
    ushort_t uh[4], ul[4];
    #pragma unroll
    for (int j = 0; j < 4; ++j) {
      int b = m0 + rb + j;
      gxn[j] = __builtin_nontemporal_load(gxt + (size_t)b * G3 + 2048 + c);
      uh[j] = hH[par * BH + b * HDIM + c];
      ul[j] = hL[par * BH + b * HDIM + c];
    }
    const ushort_t* ha = hH + par * BH + (size_t)(m0 + lr) * HDIM + lk;
    const ushort_t* la = hL + par * BH + (size_t)(m0 + lr) * HDIM + lk;

    f32x4 accR = (f32x4){0,0,0,0}, accZ = (f32x4){0,0,0,0};
    {
      sh8 b0H[8], b0L[8], b1H[8], b1L[8];
      LOADA(b0H, b0L, ha, la, 0)
      LOADA(b1H, b1L, ha, la, 8)
      MFRZ(b0H, b0L, 0)
      LOADA(b0H, b0L, ha, la, 16)
      MFRZ(b1H, b1L, 8)
      LOADA(b1H, b1L, ha, la, 24)
      MFRZ(b0H, b0L, 16)
      MFRZ(b1H, b1L, 24)
    }

    float zreg[4], hold[4];
    #pragma unroll
    for (int j = 0; j < 4; ++j) {
      int b = m0 + rb + j;
      hold[j] = bf2f(uh[j]) + bf2f(ul[j]);
      float pr = accR[j] + gxr[j] + br;
      float pz = accZ[j] + gxz[j] + bz;
      float r = 1.f / (1.f + __expf(-pr));
      zreg[j] = 1.f / (1.f + __expf(-pz));
      float rhv = r * hold[j];
      ushort_t hi = f2bf(rhv);
      __builtin_nontemporal_store(hi, &rhH[b * HDIM + c]);
      __builtin_nontemporal_store(f2bf(rhv - bf2f(hi)), &rhL[b * HDIM + c]);
    }
    gbar(cnt, ++bar * 64);

    // ---- stage 2: issue gx r,z for t+1, then pipelined n GEMM ----
    {
      int tn = (t + 1 < SEQL) ? t + 1 : t;
      const float* gxn2 = gx + (size_t)tn * (BATCH * G3);
      #pragma unroll
      for (int j = 0; j < 4; ++j) {
        int b = m0 + rb + j;
        gxr[j] = __builtin_nontemporal_load(gxn2 + (size_t)b * G3 + c);
        gxz[j] = __builtin_nontemporal_load(gxn2 + (size_t)b * G3 + 1024 + c);
      }
    }
    const ushort_t* ra = rhH + (size_t)(m0 + lr) * HDIM + lk;
    const ushort_t* rl = rhL + (size_t)(m0 + lr) * HDIM + lk;

    f32x4 accN = (f32x4){0,0,0,0};
    {
      sh8 b0H[8], b0L[8], b1H[8], b1L[8];
      LOADA(b0H, b0L, ra, rl, 0)
      LOADA(b1H, b1L, ra, rl, 8)
      MFN(b0H, b0L, 0)
      LOADA(b0H, b0L, ra, rl, 16)
      MFN(b1H, b1L, 8)
      LOADA(b1H, b1L, ra, rl, 24)
      MFN(b0H, b0L, 16)
      MFN(b1H, b1L, 24)
    }

    ushort_t* hHn = hH + (par ^ 1) * BH;
    ushort_t* hLn = hL + (par ^ 1) * BH;
    #pragma unroll
    for (int j = 0; j < 4; ++j) {
      int b = m0 + rb + j;
      float pn = accN[j] + gxn[j] + bn;
      float n = tanhf(pn);
      float z = zreg[j];
      float hnew = (1.f - z) * n + z * hold[j];
      __builtin_nontemporal_store(hnew, &Y[(size_t)t * BH + b * HDIM + c]);
      ushort_t hi = f2bf(hnew);
      __builtin_nontemporal_store(hi, &hHn[b * HDIM + c]);
      __builtin_nontemporal_store(f2bf(hnew - bf2f(hi)), &hLn[b * HDIM + c]);
      if (t == SEQL - 1) __builtin_nontemporal_store(hnew, &Yh[b * HDIM + c]);
    }
    gbar(cnt, ++bar * 64);
  }
}

// ---------------- launch ----------------
extern "C" void kernel_launch(void* const* d_in, const int* in_sizes, int n_in,
                              void* d_out, int out_size, void* d_ws, size_t ws_size,
                              hipStream_t stream) {
  const float* input = (const float*)d_in[0];
  const float* h0    = (const float*)d_in[1];
  const float* wih   = (const float*)d_in[2];
  const float* whh   = (const float*)d_in[3];
  const float* bih   = (const float*)d_in[4];
  const float* bhh   = (const float*)d_in[5];

  char* ws = (char*)d_ws;
  size_t o = 0;
  float* gx = (float*)(ws + o);         o += (size_t)AROWS * G3 * 4;
  ushort_t* WihH = (ushort_t*)(ws + o); o += (size_t)G3 * HDIM * 2;
  ushort_t* WihL = (ushort_t*)(ws + o); o += (size_t)G3 * HDIM * 2;
  ushort_t* WhhH = (ushort_t*)(ws + o); o += (size_t)G3 * HDIM * 2;
  ushort_t* WhhL = (ushort_t*)(ws + o); o += (size_t)G3 * HDIM * 2;
  ushort_t* hH = (ushort_t*)(ws + o);   o += 2 * (size_t)BH * 2;
  ushort_t* hL = (ushort_t*)(ws + o);   o += 2 * (size_t)BH * 2;
  ushort_t* rhH = (ushort_t*)(ws + o);  o += (size_t)BH * 2;
  ushort_t* rhL = (ushort_t*)(ws + o);  o += (size_t)BH * 2;
  unsigned* cnt = (unsigned*)(ws + o);  o += 256;

  float* Y  = (float*)d_out;
  float* Yh = (float*)d_out + (size_t)YSZ;

  hipFuncSetAttribute((const void*)gru_rec,
                      hipFuncAttributeMaxDynamicSharedMemorySize, 131072);

  hipMemsetAsync(cnt, 0, 256, stream);
  cvt_kernel<<<2048, 256, 0, stream>>>(wih, whh, h0, WihH, WihL, WhhH, WhhL, hH, hL);
  gemm_gx<<<(AROWS / 128) * (G3 / 128), 256, 0, stream>>>(input, WihH, WihL, bih, gx);
  gru_rec<<<64, 256, 131072, stream>>>(gx, WhhH, WhhL, bhh, hH, hL, rhH, rhL, Y, Yh, cnt);
}

// Round 4
// 15736.867 us; speedup vs baseline: 1.0448x; 1.0448x over previous
//
#include <hip/hip_runtime.h>

typedef unsigned short ushort_t;
typedef short sh8 __attribute__((ext_vector_type(8)));     // 8 bf16 (4 VGPR)
typedef float f32x4 __attribute__((ext_vector_type(4)));   // 4 fp32 acc

#define MFMA16(a,b,c) __builtin_amdgcn_mfma_f32_16x16x32_bf16((a),(b),(c),0,0,0)

#define SEQL   512
#define BATCH  64
#define HDIM   1024
#define G3     3072
#define AROWS  (SEQL*BATCH)          // 32768
#define YSZ    (SEQL*BATCH*HDIM)     // 33554432
#define BH     (BATCH*HDIM)          // 65536
#define NWG    64

__device__ __forceinline__ ushort_t f2bf(float x) {
  unsigned u = __float_as_uint(x);
  u += 0x7FFFu + ((u >> 16) & 1u);    // RNE
  return (ushort_t)(u >> 16);
}
__device__ __forceinline__ float bf2f(ushort_t h) {
  return __uint_as_float(((unsigned)h) << 16);
}

// ---------------- conversion / init ----------------
__global__ void cvt_kernel(const float* __restrict__ wih, const float* __restrict__ whh,
                           const float* __restrict__ h0,
                           ushort_t* __restrict__ WihH, ushort_t* __restrict__ WihL,
                           ushort_t* __restrict__ WhhH, ushort_t* __restrict__ WhhL,
                           ushort_t* __restrict__ hH, ushort_t* __restrict__ hL) {
  const int NW = G3 * HDIM;
  int i0 = blockIdx.x * blockDim.x + threadIdx.x;
  int stride = gridDim.x * blockDim.x;
  for (int i = i0; i < NW; i += stride) {
    float x = wih[i]; ushort_t h = f2bf(x);
    WihH[i] = h; WihL[i] = f2bf(x - bf2f(h));
    float y = whh[i]; ushort_t g = f2bf(y);
    WhhH[i] = g; WhhL[i] = f2bf(y - bf2f(g));
  }
  for (int i = i0; i < BH; i += stride) {
    float x = h0[i];
    ushort_t h = f2bf(x); hH[i] = h; hL[i] = f2bf(x - bf2f(h));
  }
}

// ---------------- phase 1: gx = input @ W_ih^T + b_ih (3-term bf16) ----------------
__global__ __launch_bounds__(256) void gemm_gx(
    const float* __restrict__ A,            // [32768][1024] fp32
    const ushort_t* __restrict__ BHp, const ushort_t* __restrict__ BLp, // [3072][1024]
    const float* __restrict__ bias,         // [3072]
    float* __restrict__ gx)                 // [32768][3072]
{
  int bid = blockIdx.x;
  int mt = bid / 24, nt = bid % 24;
  int w = threadIdx.x >> 6, l = threadIdx.x & 63;
  int lr = l & 15, lk = (l >> 4) * 8;

  f32x4 acc[2][8];
  #pragma unroll
  for (int mi = 0; mi < 2; ++mi)
    #pragma unroll
    for (int ni = 0; ni < 8; ++ni) acc[mi][ni] = (f32x4){0.f, 0.f, 0.f, 0.f};

  int arow0 = mt * 128 + w * 32 + lr;
  int brow0 = nt * 128 + lr;

  for (int k0 = 0; k0 < HDIM; k0 += 32) {
    int ka = k0 + lk;
    sh8 aH[2], aL[2];
    #pragma unroll
    for (int mi = 0; mi < 2; ++mi) {
      const float* ap = A + (size_t)(arow0 + mi * 16) * HDIM + ka;
      float4 x0 = *(const float4*)ap;
      float4 x1 = *(const float4*)(ap + 4);
      float xs[8] = {x0.x, x0.y, x0.z, x0.w, x1.x, x1.y, x1.z, x1.w};
      #pragma unroll
      for (int j = 0; j < 8; ++j) {
        ushort_t h = f2bf(xs[j]);
        aH[mi][j] = (short)h;
        aL[mi][j] = (short)f2bf(xs[j] - bf2f(h));
      }
    }
    #pragma unroll
    for (int ni = 0; ni < 8; ++ni) {
      const ushort_t* bh = BHp + (size_t)(brow0 + ni * 16) * HDIM + ka;
      const ushort_t* bl = BLp + (size_t)(brow0 + ni * 16) * HDIM + ka;
      sh8 bHf = *(const sh8*)bh;
      sh8 bLf = *(const sh8*)bl;
      #pragma unroll
      for (int mi = 0; mi < 2; ++mi) {
        acc[mi][ni] = MFMA16(aH[mi], bHf, acc[mi][ni]);
        acc[mi][ni] = MFMA16(aH[mi], bLf, acc[mi][ni]);
        acc[mi][ni] = MFMA16(aL[mi], bHf, acc[mi][ni]);
      }
    }
  }
  int rb = (l >> 4) * 4;
  #pragma unroll
  for (int mi = 0; mi < 2; ++mi)
    #pragma unroll
    for (int ni = 0; ni < 8; ++ni) {
      int col = nt * 128 + ni * 16 + lr;
      float b = bias[col];
      #pragma unroll
      for (int j = 0; j < 4; ++j) {
        int row = mt * 128 + w * 32 + mi * 16 + rb + j;
        __builtin_nontemporal_store(acc[mi][ni][j] + b, &gx[(size_t)row * G3 + col]);
      }
    }
}

// ---------------- device-scope slot barrier (no same-line atomics) ----------------
// slots: NWG lines of 128B, slot[i] = last epoch WG i arrived at.
// flag : 1 line, broadcast of last completed epoch, written by WG 0 only.
__device__ __forceinline__ void gbar2(unsigned* slots, unsigned* flag, int wg, unsigned epoch) {
  __syncthreads();   // all waves' prior stores drained (compiler emits vmcnt(0) before s_barrier)
  if (wg == 0) {
    int lane = threadIdx.x;
    if (lane > 0 && lane < NWG) {
      unsigned* sp = slots + lane * 32;
      while (__hip_atomic_load(sp, __ATOMIC_RELAXED, __HIP_MEMORY_SCOPE_AGENT) < epoch)
        __builtin_amdgcn_s_sleep(1);
      (void)__hip_atomic_load(sp, __ATOMIC_ACQUIRE, __HIP_MEMORY_SCOPE_AGENT);
    }
    __syncthreads();
    if (threadIdx.x == 0)
      __hip_atomic_store(flag, epoch, __ATOMIC_RELEASE, __HIP_MEMORY_SCOPE_AGENT);
  } else {
    if (threadIdx.x == 0) {
      __hip_atomic_store(slots + wg * 32, epoch, __ATOMIC_RELEASE, __HIP_MEMORY_SCOPE_AGENT);
      while (__hip_atomic_load(flag, __ATOMIC_RELAXED, __HIP_MEMORY_SCOPE_AGENT) < epoch)
        __builtin_amdgcn_s_sleep(1);
      (void)__hip_atomic_load(flag, __ATOMIC_ACQUIRE, __HIP_MEMORY_SCOPE_AGENT);
    }
    __syncthreads();
  }
}

// load chunk of 8 k-iters of A (hi+lo) into register buffers (static indices)
#define LOADA(BH_, BL_, pH_, pL_, base_) \
  _Pragma("unroll") for (int ii = 0; ii < 8; ++ii) { \
    BH_[ii] = *(const sh8*)(pH_ + ((base_) + ii) * 32); \
    BL_[ii] = *(const sh8*)(pL_ + ((base_) + ii) * 32); }

#define MFRZ(BH_, BL_, base_) \
  _Pragma("unroll") for (int ii = 0; ii < 8; ++ii) { \
    int byt = ((lr << 11) + ((((base_) + ii) * 32 + lk) << 1)) ^ ((lr & 7) << 4); \
    sh8 rW = *(const sh8*)(lds + byt); \
    sh8 zW = *(const sh8*)(lds + 32768 + byt); \
    accR = MFMA16(BH_[ii], rW, accR); \
    accR = MFMA16(BL_[ii], rW, accR); \
    accZ = MFMA16(BH_[ii], zW, accZ); \
    accZ = MFMA16(BL_[ii], zW, accZ); }

#define MFN(BH_, BL_, base_) \
  _Pragma("unroll") for (int ii = 0; ii < 8; ++ii) { \
    int byt = ((lr << 11) + ((((base_) + ii) * 32 + lk) << 1)) ^ ((lr & 7) << 4); \
    sh8 nW = *(const sh8*)(lds + 65536 + byt); \
    sh8 nLo = *(const sh8*)(lds + 98304 + byt); \
    accN = MFMA16(BH_[ii], nW, accN); \
    accN = MFMA16(BH_[ii], nLo, accN); \
    accN = MFMA16(BL_[ii], nW, accN); }

// ---------------- phase 2: persistent recurrence ----------------
// 64 WGs x 256 threads. WG g owns hidden cols [16g,16g+16). Wave w owns rows [16w,16w+16).
// W_hh slices live in LDS (128KB): rH@0, zH@32K, nH@64K, nL@96K, XOR-swizzled.
__global__ __launch_bounds__(256, 1) void gru_rec(
    const float* __restrict__ gx,                 // [512][64][3072]
    const ushort_t* __restrict__ WhhH, const ushort_t* __restrict__ WhhL, // [3072][1024]
    const float* __restrict__ bias_hh,            // [3072]
    ushort_t* __restrict__ hH, ushort_t* __restrict__ hL,   // [2][64][1024]
    ushort_t* __restrict__ rhH, ushort_t* __restrict__ rhL, // [64][1024]
    float* __restrict__ Y, float* __restrict__ Yh,
    unsigned* __restrict__ slots, unsigned* __restrict__ flag)
{
  extern __shared__ char lds[];
  const int g = blockIdx.x;
  const int w = threadIdx.x >> 6, l = threadIdx.x & 63;
  const int lr = l & 15, lk = (l >> 4) * 8, rb = (l >> 4) * 4;
  const int c0 = g * 16, m0 = w * 16;
  const int c = c0 + lr;

  // ---- one-time LDS fill: 64 rows x 2KB, swizzled byte ^= (row&7)<<4 ----
  #pragma unroll
  for (int p = 0; p < 32; ++p) {
    int q = threadIdx.x + p * 256;
    int flat = q * 16;
    int lrow = flat >> 11;
    int off = flat & 2047;
    int dst = flat ^ ((lrow & 7) << 4);
    const ushort_t* src;
    if (lrow < 16)      src = WhhH + (size_t)(c0 + lrow) * HDIM;
    else if (lrow < 32) src = WhhH + (size_t)(1024 + c0 + lrow - 16) * HDIM;
    else if (lrow < 48) src = WhhH + (size_t)(2048 + c0 + lrow - 32) * HDIM;
    else                src = WhhL + (size_t)(2048 + c0 + lrow - 48) * HDIM;
    *(sh8*)(lds + dst) = *(const sh8*)(src + (off >> 1));
  }
  __syncthreads();

  const float br = bias_hh[c], bz = bias_hh[1024 + c], bn = bias_hh[2048 + c];
  unsigned bar = 0;

  // prefetch gx r,z for t=0
  float gxr[4], gxz[4], gxn[4];
  #pragma unroll
  for (int j = 0; j < 4; ++j) {
    int b = m0 + rb + j;
    gxr[j] = __builtin_nontemporal_load(gx + (size_t)b * G3 + c);
    gxz[j] = __builtin_nontemporal_load(gx + (size_t)b * G3 + 1024 + c);
  }

  for (int t = 0; t < SEQL; ++t) {
    const int par = t & 1;
    const float* gxt = gx + (size_t)t * (BATCH * G3);

    // ---- stage 1: issue gx_n + own-h loads, then pipelined r,z GEMM ----
    ushort_t uh[4], ul[4];
    #pragma unroll
    for (int j = 0; j < 4; ++j) {
      int b = m0 + rb + j;
      gxn[j] = __builtin_nontemporal_load(gxt + (size_t)b * G3 + 2048 + c);
      uh[j] = hH[par * BH + b * HDIM + c];
      ul[j] = hL[par * BH + b * HDIM + c];
    }
    const ushort_t* ha = hH + par * BH + (size_t)(m0 + lr) * HDIM + lk;
    const ushort_t* la = hL + par * BH + (size_t)(m0 + lr) * HDIM + lk;

    f32x4 accR = (f32x4){0,0,0,0}, accZ = (f32x4){0,0,0,0};
    {
      sh8 b0H[8], b0L[8], b1H[8], b1L[8];
      LOADA(b0H, b0L, ha, la, 0)
      LOADA(b1H, b1L, ha, la, 8)
      MFRZ(b0H, b0L, 0)
      LOADA(b0H, b0L, ha, la, 16)
      MFRZ(b1H, b1L, 8)
      LOADA(b1H, b1L, ha, la, 24)
      MFRZ(b0H, b0L, 16)
      MFRZ(b1H, b1L, 24)
    }

    float zreg[4], hold[4];
    #pragma unroll
    for (int j = 0; j < 4; ++j) {
      int b = m0 + rb + j;
      hold[j] = bf2f(uh[j]) + bf2f(ul[j]);
      float pr = accR[j] + gxr[j] + br;
      float pz = accZ[j] + gxz[j] + bz;
      float r = 1.f / (1.f + __expf(-pr));
      zreg[j] = 1.f / (1.f + __expf(-pz));
      float rhv = r * hold[j];
      ushort_t hi = f2bf(rhv);
      __builtin_nontemporal_store(hi, &rhH[b * HDIM + c]);
      __builtin_nontemporal_store(f2bf(rhv - bf2f(hi)), &rhL[b * HDIM + c]);
    }
    gbar2(slots, flag, g, ++bar);

    // ---- stage 2: issue gx r,z for t+1, then pipelined n GEMM ----
    {
      int tn = (t + 1 < SEQL) ? t + 1 : t;
      const float* gxn2 = gx + (size_t)tn * (BATCH * G3);
      #pragma unroll
      for (int j = 0; j < 4; ++j) {
        int b = m0 + rb + j;
        gxr[j] = __builtin_nontemporal_load(gxn2 + (size_t)b * G3 + c);
        gxz[j] = __builtin_nontemporal_load(gxn2 + (size_t)b * G3 + 1024 + c);
      }
    }
    const ushort_t* ra = rhH + (size_t)(m0 + lr) * HDIM + lk;
    const ushort_t* rl = rhL + (size_t)(m0 + lr) * HDIM + lk;

    f32x4 accN = (f32x4){0,0,0,0};
    {
      sh8 b0H[8], b0L[8], b1H[8], b1L[8];
      LOADA(b0H, b0L, ra, rl, 0)
      LOADA(b1H, b1L, ra, rl, 8)
      MFN(b0H, b0L, 0)
      LOADA(b0H, b0L, ra, rl, 16)
      MFN(b1H, b1L, 8)
      LOADA(b1H, b1L, ra, rl, 24)
      MFN(b0H, b0L, 16)
      MFN(b1H, b1L, 24)
    }

    ushort_t* hHn = hH + (par ^ 1) * BH;
    ushort_t* hLn = hL + (par ^ 1) * BH;
    #pragma unroll
    for (int j = 0; j < 4; ++j) {
      int b = m0 + rb + j;
      float pn = accN[j] + gxn[j] + bn;
      float n = tanhf(pn);
      float z = zreg[j];
      float hnew = (1.f - z) * n + z * hold[j];
      __builtin_nontemporal_store(hnew, &Y[(size_t)t * BH + b * HDIM + c]);
      ushort_t hi = f2bf(hnew);
      __builtin_nontemporal_store(hi, &hHn[b * HDIM + c]);
      __builtin_nontemporal_store(f2bf(hnew - bf2f(hi)), &hLn[b * HDIM + c]);
      if (t == SEQL - 1) __builtin_nontemporal_store(hnew, &Yh[b * HDIM + c]);
    }
    gbar2(slots, flag, g, ++bar);
  }
}

// ---------------- launch ----------------
extern "C" void kernel_launch(void* const* d_in, const int* in_sizes, int n_in,
                              void* d_out, int out_size, void* d_ws, size_t ws_size,
                              hipStream_t stream) {
  const float* input = (const float*)d_in[0];
  const float* h0    = (const float*)d_in[1];
  const float* wih   = (const float*)d_in[2];
  const float* whh   = (const float*)d_in[3];
  const float* bih   = (const float*)d_in[4];
  const float* bhh   = (const float*)d_in[5];

  char* ws = (char*)d_ws;
  size_t o = 0;
  float* gx = (float*)(ws + o);         o += (size_t)AROWS * G3 * 4;
  ushort_t* WihH = (ushort_t*)(ws + o); o += (size_t)G3 * HDIM * 2;
  ushort_t* WihL = (ushort_t*)(ws + o); o += (size_t)G3 * HDIM * 2;
  ushort_t* WhhH = (ushort_t*)(ws + o); o += (size_t)G3 * HDIM * 2;
  ushort_t* WhhL = (ushort_t*)(ws + o); o += (size_t)G3 * HDIM * 2;
  ushort_t* hH = (ushort_t*)(ws + o);   o += 2 * (size_t)BH * 2;
  ushort_t* hL = (ushort_t*)(ws + o);   o += 2 * (size_t)BH * 2;
  ushort_t* rhH = (ushort_t*)(ws + o);  o += (size_t)BH * 2;
  ushort_t* rhL = (ushort_t*)(ws + o);  o += (size_t)BH * 2;
  unsigned* slots = (unsigned*)(ws + o); o += (size_t)NWG * 128;
  unsigned* flag = (unsigned*)(ws + o);  o += 128;

  float* Y  = (float*)d_out;
  float* Yh = (float*)d_out + (size_t)YSZ;

  hipFuncSetAttribute((const void*)gru_rec,
                      hipFuncAttributeMaxDynamicSharedMemorySize, 131072);

  hipMemsetAsync(slots, 0, (size_t)NWG * 128 + 128, stream);
  cvt_kernel<<<2048, 256, 0, stream>>>(wih, whh, h0, WihH, WihL, WhhH, WhhL, hH, hL);
  gemm_gx<<<(AROWS / 128) * (G3 / 128), 256, 0, stream>>>(input, WihH, WihL, bih, gx);
  gru_rec<<<64, 256, 131072, stream>>>(gx, WhhH, WhhL, bhh, hH, hL, rhH, rhL, Y, Yh, slots, flag);
}

// Round 9
// 12024.467 us; speedup vs baseline: 1.3674x; 1.3087x over previous
//
#include <hip/hip_runtime.h>

typedef unsigned short ushort_t;
typedef short sh8 __attribute__((ext_vector_type(8)));     // 8 bf16 (4 VGPR)
typedef float f32x4 __attribute__((ext_vector_type(4)));   // 4 fp32 acc

#define MFMA16(a,b,c) __builtin_amdgcn_mfma_f32_16x16x32_bf16((a),(b),(c),0,0,0)

#define SEQL   512
#define BATCH  64
#define HDIM   1024
#define G3     3072
#define AROWS  (SEQL*BATCH)          // 32768
#define YSZ    (SEQL*BATCH*HDIM)     // 33554432
#define BH     (BATCH*HDIM)          // 65536
#define NWG    64

__device__ __forceinline__ ushort_t f2bf(float x) {
  unsigned u = __float_as_uint(x);
  u += 0x7FFFu + ((u >> 16) & 1u);    // RNE
  return (ushort_t)(u >> 16);
}
__device__ __forceinline__ float bf2f(ushort_t h) {
  return __uint_as_float(((unsigned)h) << 16);
}

// ---------------- conversion / init ----------------
__global__ void cvt_kernel(const float* __restrict__ wih, const float* __restrict__ whh,
                           const float* __restrict__ h0,
                           ushort_t* __restrict__ WihH, ushort_t* __restrict__ WihL,
                           ushort_t* __restrict__ WhhH, ushort_t* __restrict__ WhhL,
                           ushort_t* __restrict__ hH, ushort_t* __restrict__ hL) {
  const int NW = G3 * HDIM;
  int i0 = blockIdx.x * blockDim.x + threadIdx.x;
  int stride = gridDim.x * blockDim.x;
  for (int i = i0; i < NW; i += stride) {
    float x = wih[i]; ushort_t h = f2bf(x);
    WihH[i] = h; WihL[i] = f2bf(x - bf2f(h));
    float y = whh[i]; ushort_t g = f2bf(y);
    WhhH[i] = g; WhhL[i] = f2bf(y - bf2f(g));
  }
  for (int i = i0; i < BH; i += stride) {
    float x = h0[i];
    ushort_t h = f2bf(x); hH[i] = h; hL[i] = f2bf(x - bf2f(h));
  }
}

// ---------------- phase 1: gx = input @ W_ih^T + b_ih (3-term bf16) ----------------
__global__ __launch_bounds__(256) void gemm_gx(
    const float* __restrict__ A,            // [32768][1024] fp32
    const ushort_t* __restrict__ BHp, const ushort_t* __restrict__ BLp, // [3072][1024]
    const float* __restrict__ bias,         // [3072]
    float* __restrict__ gx)                 // [32768][3072]
{
  int bid = blockIdx.x;
  int mt = bid / 24, nt = bid % 24;
  int w = threadIdx.x >> 6, l = threadIdx.x & 63;
  int lr = l & 15, lk = (l >> 4) * 8;

  f32x4 acc[2][8];
  #pragma unroll
  for (int mi = 0; mi < 2; ++mi)
    #pragma unroll
    for (int ni = 0; ni < 8; ++ni) acc[mi][ni] = (f32x4){0.f, 0.f, 0.f, 0.f};

  int arow0 = mt * 128 + w * 32 + lr;
  int brow0 = nt * 128 + lr;

  for (int k0 = 0; k0 < HDIM; k0 += 32) {
    int ka = k0 + lk;
    sh8 aH[2], aL[2];
    #pragma unroll
    for (int mi = 0; mi < 2; ++mi) {
      const float* ap = A + (size_t)(arow0 + mi * 16) * HDIM + ka;
      float4 x0 = *(const float4*)ap;
      float4 x1 = *(const float4*)(ap + 4);
      float xs[8] = {x0.x, x0.y, x0.z, x0.w, x1.x, x1.y, x1.z, x1.w};
      #pragma unroll
      for (int j = 0; j < 8; ++j) {
        ushort_t h = f2bf(xs[j]);
        aH[mi][j] = (short)h;
        aL[mi][j] = (short)f2bf(xs[j] - bf2f(h));
      }
    }
    #pragma unroll
    for (int ni = 0; ni < 8; ++ni) {
      const ushort_t* bh = BHp + (size_t)(brow0 + ni * 16) * HDIM + ka;
      const ushort_t* bl = BLp + (size_t)(brow0 + ni * 16) * HDIM + ka;
      sh8 bHf = *(const sh8*)bh;
      sh8 bLf = *(const sh8*)bl;
      #pragma unroll
      for (int mi = 0; mi < 2; ++mi) {
        acc[mi][ni] = MFMA16(aH[mi], bHf, acc[mi][ni]);
        acc[mi][ni] = MFMA16(aH[mi], bLf, acc[mi][ni]);
        acc[mi][ni] = MFMA16(aL[mi], bHf, acc[mi][ni]);
      }
    }
  }
  int rb = (l >> 4) * 4;
  #pragma unroll
  for (int mi = 0; mi < 2; ++mi)
    #pragma unroll
    for (int ni = 0; ni < 8; ++ni) {
      int col = nt * 128 + ni * 16 + lr;
      float b = bias[col];
      #pragma unroll
      for (int j = 0; j < 4; ++j) {
        int row = mt * 128 + w * 32 + mi * 16 + rb + j;
        __builtin_nontemporal_store(acc[mi][ni][j] + b, &gx[(size_t)row * G3 + col]);
      }
    }
}

// ---------------- flat single-hop device barrier (function: epoch by value) ----------------
// Arrive: release-store own 128B slot. Wave 0: lane i polls slot i (relaxed),
// then ALL lanes acquire-load their slot (syncs-with every WG's release + inv caches).
__device__ __forceinline__ void gbar_flat(unsigned* slots, int g, int tid, unsigned e) {
  __syncthreads();
  if (tid < 64) {
    if (tid == 0)
      __hip_atomic_store(slots + g * 32, e, __ATOMIC_RELEASE, __HIP_MEMORY_SCOPE_AGENT);
    unsigned* sp = slots + tid * 32;
    while (__hip_atomic_load(sp, __ATOMIC_RELAXED, __HIP_MEMORY_SCOPE_AGENT) < e)
      __builtin_amdgcn_s_sleep(1);
    (void)__hip_atomic_load(sp, __ATOMIC_ACQUIRE, __HIP_MEMORY_SCOPE_AGENT);
  }
  __syncthreads();
}

// load chunk of 8 k-iters of A (hi+lo) into register buffers (static indices)
#define LOADA(BH_, BL_, pH_, pL_, base_) \
  _Pragma("unroll") for (int ii = 0; ii < 8; ++ii) { \
    BH_[ii] = *(const sh8*)(pH_ + ((base_) + ii) * 32); \
    BL_[ii] = *(const sh8*)(pL_ + ((base_) + ii) * 32); }

// load chunk of 8 k-iters of A (hi only)
#define LOADH(BH_, pH_, base_) \
  _Pragma("unroll") for (int ii = 0; ii < 8; ++ii) { \
    BH_[ii] = *(const sh8*)(pH_ + ((base_) + ii) * 32); }

#define MFRZ(BH_, BL_, base_) \
  _Pragma("unroll") for (int ii = 0; ii < 8; ++ii) { \
    int byt = ((lr << 11) + ((((base_) + ii) * 32 + lk) << 1)) ^ ((lr & 7) << 4); \
    sh8 rW = *(const sh8*)(lds + byt); \
    sh8 zW = *(const sh8*)(lds + 32768 + byt); \
    accR = MFMA16(BH_[ii], rW, accR); \
    accR = MFMA16(BL_[ii], rW, accR); \
    accZ = MFMA16(BH_[ii], zW, accZ); \
    accZ = MFMA16(BL_[ii], zW, accZ); }

#define MFN(BH_, base_) \
  _Pragma("unroll") for (int ii = 0; ii < 8; ++ii) { \
    int byt = ((lr << 11) + ((((base_) + ii) * 32 + lk) << 1)) ^ ((lr & 7) << 4); \
    sh8 nW = *(const sh8*)(lds + 65536 + byt); \
    sh8 nLo = *(const sh8*)(lds + 98304 + byt); \
    accN = MFMA16(BH_[ii], nW, accN); \
    accN = MFMA16(BH_[ii], nLo, accN); }

// ---------------- phase 2: persistent recurrence ----------------
// 64 WGs x 256 threads. WG g owns hidden cols [16g,16g+16). Wave w owns rows [16w,16w+16).
// W_hh slices in LDS (128KB): rH@0, zH@32K, nH@64K, nL@96K, XOR-swizzled.
__global__ __launch_bounds__(256, 1) void gru_rec(
    const float* __restrict__ gx,                 // [512][64][3072]
    const ushort_t* __restrict__ WhhH, const ushort_t* __restrict__ WhhL, // [3072][1024]
    const float* __restrict__ bias_hh,            // [3072]
    const float* __restrict__ h0f,                // [64][1024] fp32
    ushort_t* __restrict__ hH, ushort_t* __restrict__ hL,   // [2][64][1024]
    ushort_t* __restrict__ rhH,                   // [64][1024]
    float* __restrict__ Y, float* __restrict__ Yh,
    unsigned* __restrict__ slots)
{
  extern __shared__ char lds[];
  const int g = blockIdx.x;
  const int tid = threadIdx.x;
  const int w = tid >> 6, l = tid & 63;
  const int lr = l & 15, lk = (l >> 4) * 8, rb = (l >> 4) * 4;
  const int c0 = g * 16, m0 = w * 16;
  const int c = c0 + lr;

  // ---- one-time LDS fill: 64 rows x 2KB, swizzled byte ^= (row&7)<<4 ----
  #pragma unroll
  for (int p = 0; p < 32; ++p) {
    int q = tid + p * 256;
    int flat = q * 16;
    int lrow = flat >> 11;
    int off = flat & 2047;
    int dst = flat ^ ((lrow & 7) << 4);
    const ushort_t* src;
    if (lrow < 16)      src = WhhH + (size_t)(c0 + lrow) * HDIM;
    else if (lrow < 32) src = WhhH + (size_t)(1024 + c0 + lrow - 16) * HDIM;
    else if (lrow < 48) src = WhhH + (size_t)(2048 + c0 + lrow - 32) * HDIM;
    else                src = WhhL + (size_t)(2048 + c0 + lrow - 48) * HDIM;
    *(sh8*)(lds + dst) = *(const sh8*)(src + (off >> 1));
  }
  __syncthreads();

  const float br = bias_hh[c], bz = bias_hh[1024 + c], bn = bias_hh[2048 + c];
  unsigned bar = 0;

  // own-column h carried exactly in fp32 registers across the whole sequence
  float hold[4];
  #pragma unroll
  for (int j = 0; j < 4; ++j) hold[j] = h0f[(m0 + rb + j) * HDIM + c];

  // prefetch gx r,z for t=0
  float gxr[4], gxz[4], gxn[4];
  #pragma unroll
  for (int j = 0; j < 4; ++j) {
    int b = m0 + rb + j;
    gxr[j] = __builtin_nontemporal_load(gx + (size_t)b * G3 + c);
    gxz[j] = __builtin_nontemporal_load(gx + (size_t)b * G3 + 1024 + c);
  }

  for (int t = 0; t < SEQL; ++t) {
    const int par = t & 1;
    const float* gxt = gx + (size_t)t * (BATCH * G3);

    // ---- stage 1: issue gx_n load, then pipelined r,z GEMM ----
    #pragma unroll
    for (int j = 0; j < 4; ++j) {
      int b = m0 + rb + j;
      gxn[j] = __builtin_nontemporal_load(gxt + (size_t)b * G3 + 2048 + c);
    }
    const ushort_t* ha = hH + par * BH + (size_t)(m0 + lr) * HDIM + lk;
    const ushort_t* la = hL + par * BH + (size_t)(m0 + lr) * HDIM + lk;

    f32x4 accR = (f32x4){0,0,0,0}, accZ = (f32x4){0,0,0,0};
    {
      sh8 b0H[8], b0L[8], b1H[8], b1L[8];
      LOADA(b0H, b0L, ha, la, 0)
      LOADA(b1H, b1L, ha, la, 8)
      MFRZ(b0H, b0L, 0)
      LOADA(b0H, b0L, ha, la, 16)
      MFRZ(b1H, b1L, 8)
      LOADA(b1H, b1L, ha, la, 24)
      MFRZ(b0H, b0L, 16)
      MFRZ(b1H, b1L, 24)
    }

    float zreg[4];
    #pragma unroll
    for (int j = 0; j < 4; ++j) {
      int b = m0 + rb + j;
      float pr = accR[j] + gxr[j] + br;
      float pz = accZ[j] + gxz[j] + bz;
      float r = 1.f / (1.f + __expf(-pr));
      zreg[j] = 1.f / (1.f + __expf(-pz));
      float rhv = r * hold[j];
      __builtin_nontemporal_store(f2bf(rhv), &rhH[b * HDIM + c]);
    }
    ++bar;
    gbar_flat(slots, g, tid, bar);

    // ---- stage 2: issue gx r,z for t+1, then pipelined n GEMM (rh hi-only) ----
    {
      int tn = (t + 1 < SEQL) ? t + 1 : t;
      const float* gxn2 = gx + (size_t)tn * (BATCH * G3);
      #pragma unroll
      for (int j = 0; j < 4; ++j) {
        int b = m0 + rb + j;
        gxr[j] = __builtin_nontemporal_load(gxn2 + (size_t)b * G3 + c);
        gxz[j] = __builtin_nontemporal_load(gxn2 + (size_t)b * G3 + 1024 + c);
      }
    }
    const ushort_t* ra = rhH + (size_t)(m0 + lr) * HDIM + lk;

    f32x4 accN = (f32x4){0,0,0,0};
    {
      sh8 b0H[8], b1H[8];
      LOADH(b0H, ra, 0)
      LOADH(b1H, ra, 8)
      MFN(b0H, 0)
      LOADH(b0H, ra, 16)
      MFN(b1H, 8)
      LOADH(b1H, ra, 24)
      MFN(b0H, 16)
      MFN(b1H, 24)
    }

    ushort_t* hHn = hH + (par ^ 1) * BH;
    ushort_t* hLn = hL + (par ^ 1) * BH;
    #pragma unroll
    for (int j = 0; j < 4; ++j) {
      int b = m0 + rb + j;
      float pn = accN[j] + gxn[j] + bn;
      float n = tanhf(pn);
      float z = zreg[j];
      float hnew = (1.f - z) * n + z * hold[j];
      hold[j] = hnew;
      __builtin_nontemporal_store(hnew, &Y[(size_t)t * BH + b * HDIM + c]);
      ushort_t hi = f2bf(hnew);
      __builtin_nontemporal_store(hi, &hHn[b * HDIM + c]);
      __builtin_nontemporal_store(f2bf(hnew - bf2f(hi)), &hLn[b * HDIM + c]);
      if (t == SEQL - 1) __builtin_nontemporal_store(hnew, &Yh[b * HDIM + c]);
    }
    if (t < SEQL - 1) {
      ++bar;
      gbar_flat(slots, g, tid, bar);
    }
  }
}

// ---------------- launch ----------------
extern "C" void kernel_launch(void* const* d_in, const int* in_sizes, int n_in,
                              void* d_out, int out_size, void* d_ws, size_t ws_size,
                              hipStream_t stream) {
  const float* input = (const float*)d_in[0];
  const float* h0    = (const float*)d_in[1];
  const float* wih   = (const float*)d_in[2];
  const float* whh   = (const float*)d_in[3];
  const float* bih   = (const float*)d_in[4];
  const float* bhh   = (const float*)d_in[5];

  char* ws = (char*)d_ws;
  size_t o = 0;
  float* gx = (float*)(ws + o);         o += (size_t)AROWS * G3 * 4;
  ushort_t* WihH = (ushort_t*)(ws + o); o += (size_t)G3 * HDIM * 2;
  ushort_t* WihL = (ushort_t*)(ws + o); o += (size_t)G3 * HDIM * 2;
  ushort_t* WhhH = (ushort_t*)(ws + o); o += (size_t)G3 * HDIM * 2;
  ushort_t* WhhL = (ushort_t*)(ws + o); o += (size_t)G3 * HDIM * 2;
  ushort_t* hH = (ushort_t*)(ws + o);   o += 2 * (size_t)BH * 2;
  ushort_t* hL = (ushort_t*)(ws + o);   o += 2 * (size_t)BH * 2;
  ushort_t* rhH = (ushort_t*)(ws + o);  o += (size_t)BH * 2;
  ushort_t* rhL = (ushort_t*)(ws + o);  o += (size_t)BH * 2;   // unused (kept for layout)
  unsigned* slots = (unsigned*)(ws + o); o += (size_t)NWG * 128;
  (void)rhL;

  float* Y  = (float*)d_out;
  float* Yh = (float*)d_out + (size_t)YSZ;

  (void)hipFuncSetAttribute((const void*)gru_rec,
                            hipFuncAttributeMaxDynamicSharedMemorySize, 131072);

  (void)hipMemsetAsync(slots, 0, (size_t)NWG * 128, stream);
  cvt_kernel<<<2048, 256, 0, stream>>>(wih, whh, h0, WihH, WihL, WhhH, WhhL, hH, hL);
  gemm_gx<<<(AROWS / 128) * (G3 / 128), 256, 0, stream>>>(input, WihH, WihL, bih, gx);
  gru_rec<<<64, 256, 131072, stream>>>(gx, WhhH, WhhL, bhh, h0, hH, hL, rhH, Y, Yh, slots);
}

// Round 10
// 8859.130 us; speedup vs baseline: 1.8559x; 1.3573x over previous
//
#include <hip/hip_runtime.h>

typedef unsigned short ushort_t;
typedef short sh8 __attribute__((ext_vector_type(8)));     // 8 bf16 (4 VGPR)
typedef float f32x4 __attribute__((ext_vector_type(4)));   // 4 fp32 acc

#define MFMA16(a,b,c) __builtin_amdgcn_mfma_f32_16x16x32_bf16((a),(b),(c),0,0,0)

#define SEQL   512
#define BATCH  64
#define HDIM   1024
#define G3     3072
#define AROWS  (SEQL*BATCH)          // 32768
#define YSZ    (SEQL*BATCH*HDIM)     // 33554432
#define BH     (BATCH*HDIM)          // 65536
#define NWG    64

__device__ __forceinline__ ushort_t f2bf(float x) {
  unsigned u = __float_as_uint(x);
  u += 0x7FFFu + ((u >> 16) & 1u);    // RNE
  return (ushort_t)(u >> 16);
}
__device__ __forceinline__ float bf2f(ushort_t h) {
  return __uint_as_float(((unsigned)h) << 16);
}

// ---------------- conversion / init ----------------
__global__ void cvt_kernel(const float* __restrict__ wih, const float* __restrict__ whh,
                           const float* __restrict__ h0,
                           ushort_t* __restrict__ WihH, ushort_t* __restrict__ WihL,
                           ushort_t* __restrict__ WhhH, ushort_t* __restrict__ WhhL,
                           ushort_t* __restrict__ hH) {
  const int NW = G3 * HDIM;
  int i0 = blockIdx.x * blockDim.x + threadIdx.x;
  int stride = gridDim.x * blockDim.x;
  for (int i = i0; i < NW; i += stride) {
    float x = wih[i]; ushort_t h = f2bf(x);
    WihH[i] = h; WihL[i] = f2bf(x - bf2f(h));
    float y = whh[i]; ushort_t g = f2bf(y);
    WhhH[i] = g; WhhL[i] = f2bf(y - bf2f(g));
  }
  for (int i = i0; i < BH; i += stride) {
    hH[i] = f2bf(h0[i]);
  }
}

// ---------------- phase 1: gx = input @ W_ih^T + b_ih (3-term bf16) ----------------
__global__ __launch_bounds__(256) void gemm_gx(
    const float* __restrict__ A,            // [32768][1024] fp32
    const ushort_t* __restrict__ BHp, const ushort_t* __restrict__ BLp, // [3072][1024]
    const float* __restrict__ bias,         // [3072]
    float* __restrict__ gx)                 // [32768][3072]
{
  int bid = blockIdx.x;
  int mt = bid / 24, nt = bid % 24;
  int w = threadIdx.x >> 6, l = threadIdx.x & 63;
  int lr = l & 15, lk = (l >> 4) * 8;

  f32x4 acc[2][8];
  #pragma unroll
  for (int mi = 0; mi < 2; ++mi)
    #pragma unroll
    for (int ni = 0; ni < 8; ++ni) acc[mi][ni] = (f32x4){0.f, 0.f, 0.f, 0.f};

  int arow0 = mt * 128 + w * 32 + lr;
  int brow0 = nt * 128 + lr;

  for (int k0 = 0; k0 < HDIM; k0 += 32) {
    int ka = k0 + lk;
    sh8 aH[2], aL[2];
    #pragma unroll
    for (int mi = 0; mi < 2; ++mi) {
      const float* ap = A + (size_t)(arow0 + mi * 16) * HDIM + ka;
      float4 x0 = *(const float4*)ap;
      float4 x1 = *(const float4*)(ap + 4);
      float xs[8] = {x0.x, x0.y, x0.z, x0.w, x1.x, x1.y, x1.z, x1.w};
      #pragma unroll
      for (int j = 0; j < 8; ++j) {
        ushort_t h = f2bf(xs[j]);
        aH[mi][j] = (short)h;
        aL[mi][j] = (short)f2bf(xs[j] - bf2f(h));
      }
    }
    #pragma unroll
    for (int ni = 0; ni < 8; ++ni) {
      const ushort_t* bh = BHp + (size_t)(brow0 + ni * 16) * HDIM + ka;
      const ushort_t* bl = BLp + (size_t)(brow0 + ni * 16) * HDIM + ka;
      sh8 bHf = *(const sh8*)bh;
      sh8 bLf = *(const sh8*)bl;
      #pragma unroll
      for (int mi = 0; mi < 2; ++mi) {
        acc[mi][ni] = MFMA16(aH[mi], bHf, acc[mi][ni]);
        acc[mi][ni] = MFMA16(aH[mi], bLf, acc[mi][ni]);
        acc[mi][ni] = MFMA16(aL[mi], bHf, acc[mi][ni]);
      }
    }
  }
  int rb = (l >> 4) * 4;
  #pragma unroll
  for (int mi = 0; mi < 2; ++mi)
    #pragma unroll
    for (int ni = 0; ni < 8; ++ni) {
      int col = nt * 128 + ni * 16 + lr;
      float b = bias[col];
      #pragma unroll
      for (int j = 0; j < 4; ++j) {
        int row = mt * 128 + w * 32 + mi * 16 + rb + j;
        __builtin_nontemporal_store(acc[mi][ni][j] + b, &gx[(size_t)row * G3 + col]);
      }
    }
}

// ---------------- flat single-hop device barrier (function: epoch by value) ----------------
__device__ __forceinline__ void gbar_flat(unsigned* slots, int g, int tid, unsigned e) {
  __syncthreads();
  if (tid < 64) {
    if (tid == 0)
      __hip_atomic_store(slots + g * 32, e, __ATOMIC_RELEASE, __HIP_MEMORY_SCOPE_AGENT);
    unsigned* sp = slots + tid * 32;
    while (__hip_atomic_load(sp, __ATOMIC_RELAXED, __HIP_MEMORY_SCOPE_AGENT) < e)
      __builtin_amdgcn_s_sleep(1);
    (void)__hip_atomic_load(sp, __ATOMIC_ACQUIRE, __HIP_MEMORY_SCOPE_AGENT);
  }
  __syncthreads();
}

// load chunk of 8 k-iters of A (hi only) into register buffers (static indices)
#define LOADH(BH_, pH_, base_) \
  _Pragma("unroll") for (int ii = 0; ii < 8; ++ii) { \
    BH_[ii] = *(const sh8*)(pH_ + ((base_) + ii) * 32); }

// r,z: hi-h x hi-W (2 MFMA/iter)
#define MFRZ(BH_, base_) \
  _Pragma("unroll") for (int ii = 0; ii < 8; ++ii) { \
    int byt = ((lr << 11) + ((((base_) + ii) * 32 + lk) << 1)) ^ ((lr & 7) << 4); \
    sh8 rW = *(const sh8*)(lds + byt); \
    sh8 zW = *(const sh8*)(lds + 32768 + byt); \
    accR = MFMA16(BH_[ii], rW, accR); \
    accZ = MFMA16(BH_[ii], zW, accZ); }

// n: hi-rh x (hi+lo W) (2 MFMA/iter)
#define MFN(BH_, base_) \
  _Pragma("unroll") for (int ii = 0; ii < 8; ++ii) { \
    int byt = ((lr << 11) + ((((base_) + ii) * 32 + lk) << 1)) ^ ((lr & 7) << 4); \
    sh8 nW = *(const sh8*)(lds + 65536 + byt); \
    sh8 nLo = *(const sh8*)(lds + 98304 + byt); \
    accN = MFMA16(BH_[ii], nW, accN); \
    accN = MFMA16(BH_[ii], nLo, accN); }

// ---------------- phase 2: persistent recurrence ----------------
// 64 WGs x 256 threads. WG g owns hidden cols [16g,16g+16). Wave w owns rows [16w,16w+16).
// W_hh slices in LDS (128KB): rH@0, zH@32K, nH@64K, nL@96K, XOR-swizzled.
// Exchange (hH, rhH) via NORMAL stores -> dirty L2 -> release wbL2 -> L3; consumers
// post-acquire load from L3 (NOT HBM). Y/gx stay nontemporal (streams).
__global__ __launch_bounds__(256, 1) void gru_rec(
    const float* __restrict__ gx,                 // [512][64][3072]
    const ushort_t* __restrict__ WhhH, const ushort_t* __restrict__ WhhL, // [3072][1024]
    const float* __restrict__ bias_hh,            // [3072]
    const float* __restrict__ h0f,                // [64][1024] fp32
    ushort_t* __restrict__ hH,                    // [2][64][1024]
    ushort_t* __restrict__ rhH,                   // [64][1024]
    float* __restrict__ Y, float* __restrict__ Yh,
    unsigned* __restrict__ slots)
{
  extern __shared__ char lds[];
  const int g = blockIdx.x;
  const int tid = threadIdx.x;
  const int w = tid >> 6, l = tid & 63;
  const int lr = l & 15, lk = (l >> 4) * 8, rb = (l >> 4) * 4;
  const int c0 = g * 16, m0 = w * 16;
  const int c = c0 + lr;

  // ---- one-time LDS fill: 64 rows x 2KB, swizzled byte ^= (row&7)<<4 ----
  #pragma unroll
  for (int p = 0; p < 32; ++p) {
    int q = tid + p * 256;
    int flat = q * 16;
    int lrow = flat >> 11;
    int off = flat & 2047;
    int dst = flat ^ ((lrow & 7) << 4);
    const ushort_t* src;
    if (lrow < 16)      src = WhhH + (size_t)(c0 + lrow) * HDIM;
    else if (lrow < 32) src = WhhH + (size_t)(1024 + c0 + lrow - 16) * HDIM;
    else if (lrow < 48) src = WhhH + (size_t)(2048 + c0 + lrow - 32) * HDIM;
    else                src = WhhL + (size_t)(2048 + c0 + lrow - 48) * HDIM;
    *(sh8*)(lds + dst) = *(const sh8*)(src + (off >> 1));
  }
  __syncthreads();

  const float br = bias_hh[c], bz = bias_hh[1024 + c], bn = bias_hh[2048 + c];
  unsigned bar = 0;

  // own-column h carried exactly in fp32 registers across the whole sequence
  float hold[4];
  #pragma unroll
  for (int j = 0; j < 4; ++j) hold[j] = h0f[(m0 + rb + j) * HDIM + c];

  // prefetch gx r,z for t=0
  float gxr[4], gxz[4], gxn[4];
  #pragma unroll
  for (int j = 0; j < 4; ++j) {
    int b = m0 + rb + j;
    gxr[j] = __builtin_nontemporal_load(gx + (size_t)b * G3 + c);
    gxz[j] = __builtin_nontemporal_load(gx + (size_t)b * G3 + 1024 + c);
  }

  for (int t = 0; t < SEQL; ++t) {
    const int par = t & 1;
    const float* gxt = gx + (size_t)t * (BATCH * G3);

    // ---- stage 1: issue gx_n load, then pipelined r,z GEMM (h hi-only) ----
    #pragma unroll
    for (int j = 0; j < 4; ++j) {
      int b = m0 + rb + j;
      gxn[j] = __builtin_nontemporal_load(gxt + (size_t)b * G3 + 2048 + c);
    }
    const ushort_t* ha = hH + par * BH + (size_t)(m0 + lr) * HDIM + lk;

    f32x4 accR = (f32x4){0,0,0,0}, accZ = (f32x4){0,0,0,0};
    {
      sh8 b0H[8], b1H[8];
      LOADH(b0H, ha, 0)
      LOADH(b1H, ha, 8)
      MFRZ(b0H, 0)
      LOADH(b0H, ha, 16)
      MFRZ(b1H, 8)
      LOADH(b1H, ha, 24)
      MFRZ(b0H, 16)
      MFRZ(b1H, 24)
    }

    float zreg[4];
    #pragma unroll
    for (int j = 0; j < 4; ++j) {
      int b = m0 + rb + j;
      float pr = accR[j] + gxr[j] + br;
      float pz = accZ[j] + gxz[j] + bz;
      float r = 1.f / (1.f + __expf(-pr));
      zreg[j] = 1.f / (1.f + __expf(-pz));
      rhH[b * HDIM + c] = f2bf(r * hold[j]);      // normal store (stays cached)
    }
    ++bar;
    gbar_flat(slots, g, tid, bar);

    // ---- stage 2: issue gx r,z for t+1, then pipelined n GEMM (rh hi-only) ----
    {
      int tn = (t + 1 < SEQL) ? t + 1 : t;
      const float* gxn2 = gx + (size_t)tn * (BATCH * G3);
      #pragma unroll
      for (int j = 0; j < 4; ++j) {
        int b = m0 + rb + j;
        gxr[j] = __builtin_nontemporal_load(gxn2 + (size_t)b * G3 + c);
        gxz[j] = __builtin_nontemporal_load(gxn2 + (size_t)b * G3 + 1024 + c);
      }
    }
    const ushort_t* ra = rhH + (size_t)(m0 + lr) * HDIM + lk;

    f32x4 accN = (f32x4){0,0,0,0};
    {
      sh8 b0H[8], b1H[8];
      LOADH(b0H, ra, 0)
      LOADH(b1H, ra, 8)
      MFN(b0H, 0)
      LOADH(b0H, ra, 16)
      MFN(b1H, 8)
      LOADH(b1H, ra, 24)
      MFN(b0H, 16)
      MFN(b1H, 24)
    }

    ushort_t* hHn = hH + (par ^ 1) * BH;
    #pragma unroll
    for (int j = 0; j < 4; ++j) {
      int b = m0 + rb + j;
      float pn = accN[j] + gxn[j] + bn;
      float n = tanhf(pn);
      float z = zreg[j];
      float hnew = (1.f - z) * n + z * hold[j];
      hold[j] = hnew;
      __builtin_nontemporal_store(hnew, &Y[(size_t)t * BH + b * HDIM + c]);
      hHn[b * HDIM + c] = f2bf(hnew);             // normal store (stays cached)
      if (t == SEQL - 1) __builtin_nontemporal_store(hnew, &Yh[b * HDIM + c]);
    }
    if (t < SEQL - 1) {
      ++bar;
      gbar_flat(slots, g, tid, bar);
    }
  }
}

// ---------------- launch ----------------
extern "C" void kernel_launch(void* const* d_in, const int* in_sizes, int n_in,
                              void* d_out, int out_size, void* d_ws, size_t ws_size,
                              hipStream_t stream) {
  const float* input = (const float*)d_in[0];
  const float* h0    = (const float*)d_in[1];
  const float* wih   = (const float*)d_in[2];
  const float* whh   = (const float*)d_in[3];
  const float* bih   = (const float*)d_in[4];
  const float* bhh   = (const float*)d_in[5];

  char* ws = (char*)d_ws;
  size_t o = 0;
  float* gx = (float*)(ws + o);         o += (size_t)AROWS * G3 * 4;
  ushort_t* WihH = (ushort_t*)(ws + o); o += (size_t)G3 * HDIM * 2;
  ushort_t* WihL = (ushort_t*)(ws + o); o += (size_t)G3 * HDIM * 2;
  ushort_t* WhhH = (ushort_t*)(ws + o); o += (size_t)G3 * HDIM * 2;
  ushort_t* WhhL = (ushort_t*)(ws + o); o += (size_t)G3 * HDIM * 2;
  ushort_t* hH = (ushort_t*)(ws + o);   o += 2 * (size_t)BH * 2;
  ushort_t* rhH = (ushort_t*)(ws + o);  o += (size_t)BH * 2;
  unsigned* slots = (unsigned*)(ws + o); o += (size_t)NWG * 128;

  float* Y  = (float*)d_out;
  float* Yh = (float*)d_out + (size_t)YSZ;

  (void)hipFuncSetAttribute((const void*)gru_rec,
                            hipFuncAttributeMaxDynamicSharedMemorySize, 131072);

  (void)hipMemsetAsync(slots, 0, (size_t)NWG * 128, stream);
  cvt_kernel<<<2048, 256, 0, stream>>>(wih, whh, h0, WihH, WihL, WhhH, WhhL, hH);
  gemm_gx<<<(AROWS / 128) * (G3 / 128), 256, 0, stream>>>(input, WihH, WihL, bih, gx);
  gru_rec<<<64, 256, 131072, stream>>>(gx, WhhH, WhhL, bhh, h0, hH, rhH, Y, Yh, slots);
}

// Round 11
// 8765.251 us; speedup vs baseline: 1.8758x; 1.0107x over previous
//
#include <hip/hip_runtime.h>

typedef unsigned short ushort_t;
typedef short sh8 __attribute__((ext_vector_type(8)));     // 8 bf16 (4 VGPR)
typedef float f32x4 __attribute__((ext_vector_type(4)));   // 4 fp32 acc

#define MFMA16(a,b,c) __builtin_amdgcn_mfma_f32_16x16x32_bf16((a),(b),(c),0,0,0)

#define SEQL   512
#define BATCH  64
#define HDIM   1024
#define G3     3072
#define AROWS  (SEQL*BATCH)          // 32768
#define YSZ    (SEQL*BATCH*HDIM)     // 33554432
#define BH     (BATCH*HDIM)          // 65536
#define NWG    64

__device__ __forceinline__ ushort_t f2bf(float x) {
  unsigned u = __float_as_uint(x);
  u += 0x7FFFu + ((u >> 16) & 1u);    // RNE
  return (ushort_t)(u >> 16);
}
__device__ __forceinline__ float bf2f(ushort_t h) {
  return __uint_as_float(((unsigned)h) << 16);
}

// ---------------- conversion / init ----------------
__global__ void cvt_kernel(const float* __restrict__ wih, const float* __restrict__ whh,
                           const float* __restrict__ h0,
                           ushort_t* __restrict__ WihH, ushort_t* __restrict__ WihL,
                           ushort_t* __restrict__ WhhH, ushort_t* __restrict__ WhhL,
                           ushort_t* __restrict__ hH) {
  const int NW = G3 * HDIM;
  int i0 = blockIdx.x * blockDim.x + threadIdx.x;
  int stride = gridDim.x * blockDim.x;
  for (int i = i0; i < NW; i += stride) {
    float x = wih[i]; ushort_t h = f2bf(x);
    WihH[i] = h; WihL[i] = f2bf(x - bf2f(h));
    float y = whh[i]; ushort_t g = f2bf(y);
    WhhH[i] = g; WhhL[i] = f2bf(y - bf2f(g));
  }
  for (int i = i0; i < BH; i += stride) {
    hH[i] = f2bf(h0[i]);
  }
}

// ---------------- phase 1: gx = input @ W_ih^T + b_ih (3-term bf16) ----------------
__global__ __launch_bounds__(256) void gemm_gx(
    const float* __restrict__ A,            // [32768][1024] fp32
    const ushort_t* __restrict__ BHp, const ushort_t* __restrict__ BLp, // [3072][1024]
    const float* __restrict__ bias,         // [3072]
    float* __restrict__ gx)                 // [32768][3072]
{
  int bid = blockIdx.x;
  int mt = bid / 24, nt = bid % 24;
  int w = threadIdx.x >> 6, l = threadIdx.x & 63;
  int lr = l & 15, lk = (l >> 4) * 8;

  f32x4 acc[2][8];
  #pragma unroll
  for (int mi = 0; mi < 2; ++mi)
    #pragma unroll
    for (int ni = 0; ni < 8; ++ni) acc[mi][ni] = (f32x4){0.f, 0.f, 0.f, 0.f};

  int arow0 = mt * 128 + w * 32 + lr;
  int brow0 = nt * 128 + lr;

  for (int k0 = 0; k0 < HDIM; k0 += 32) {
    int ka = k0 + lk;
    sh8 aH[2], aL[2];
    #pragma unroll
    for (int mi = 0; mi < 2; ++mi) {
      const float* ap = A + (size_t)(arow0 + mi * 16) * HDIM + ka;
      float4 x0 = *(const float4*)ap;
      float4 x1 = *(const float4*)(ap + 4);
      float xs[8] = {x0.x, x0.y, x0.z, x0.w, x1.x, x1.y, x1.z, x1.w};
      #pragma unroll
      for (int j = 0; j < 8; ++j) {
        ushort_t h = f2bf(xs[j]);
        aH[mi][j] = (short)h;
        aL[mi][j] = (short)f2bf(xs[j] - bf2f(h));
      }
    }
    #pragma unroll
    for (int ni = 0; ni < 8; ++ni) {
      const ushort_t* bh = BHp + (size_t)(brow0 + ni * 16) * HDIM + ka;
      const ushort_t* bl = BLp + (size_t)(brow0 + ni * 16) * HDIM + ka;
      sh8 bHf = *(const sh8*)bh;
      sh8 bLf = *(const sh8*)bl;
      #pragma unroll
      for (int mi = 0; mi < 2; ++mi) {
        acc[mi][ni] = MFMA16(aH[mi], bHf, acc[mi][ni]);
        acc[mi][ni] = MFMA16(aH[mi], bLf, acc[mi][ni]);
        acc[mi][ni] = MFMA16(aL[mi], bHf, acc[mi][ni]);
      }
    }
  }
  int rb = (l >> 4) * 4;
  #pragma unroll
  for (int mi = 0; mi < 2; ++mi)
    #pragma unroll
    for (int ni = 0; ni < 8; ++ni) {
      int col = nt * 128 + ni * 16 + lr;
      float b = bias[col];
      #pragma unroll
      for (int j = 0; j < 4; ++j) {
        int row = mt * 128 + w * 32 + mi * 16 + rb + j;
        __builtin_nontemporal_store(acc[mi][ni][j] + b, &gx[(size_t)row * G3 + col]);
      }
    }
}

// ---------------- flat single-hop device barrier (function: epoch by value) ----------------
__device__ __forceinline__ void gbar_flat(unsigned* slots, int g, int tid, unsigned e) {
  __syncthreads();
  if (tid < 64) {
    if (tid == 0)
      __hip_atomic_store(slots + g * 32, e, __ATOMIC_RELEASE, __HIP_MEMORY_SCOPE_AGENT);
    unsigned* sp = slots + tid * 32;
    while (__hip_atomic_load(sp, __ATOMIC_RELAXED, __HIP_MEMORY_SCOPE_AGENT) < e)
      __builtin_amdgcn_s_sleep(1);
    (void)__hip_atomic_load(sp, __ATOMIC_ACQUIRE, __HIP_MEMORY_SCOPE_AGENT);
  }
  __syncthreads();
}

// ---------------- phase 2: persistent recurrence ----------------
// 64 WGs x 256 threads. WG g owns hidden cols [16g,16g+16). Wave w owns rows [16w,16w+16).
// W_hh slices in LDS (128KB): rH@0, zH@32K, nH@64K, nL@96K, XOR-swizzled.
// A-operand (h / rh) loaded as ONE 32-deep burst (128 VGPRs) -> single L3 round trip.
// gx for t+1 prefetched during stage 2 of t (fully off critical path).
__global__ __launch_bounds__(256, 1) void gru_rec(
    const float* __restrict__ gx,                 // [512][64][3072]
    const ushort_t* __restrict__ WhhH, const ushort_t* __restrict__ WhhL, // [3072][1024]
    const float* __restrict__ bias_hh,            // [3072]
    const float* __restrict__ h0f,                // [64][1024] fp32
    ushort_t* __restrict__ hH,                    // [2][64][1024]
    ushort_t* __restrict__ rhH,                   // [64][1024]
    float* __restrict__ Y, float* __restrict__ Yh,
    unsigned* __restrict__ slots)
{
  extern __shared__ char lds[];
  const int g = blockIdx.x;
  const int tid = threadIdx.x;
  const int w = tid >> 6, l = tid & 63;
  const int lr = l & 15, lk = (l >> 4) * 8, rb = (l >> 4) * 4;
  const int c0 = g * 16, m0 = w * 16;
  const int c = c0 + lr;

  // ---- one-time LDS fill: 64 rows x 2KB, swizzled byte ^= (row&7)<<4 ----
  #pragma unroll
  for (int p = 0; p < 32; ++p) {
    int q = tid + p * 256;
    int flat = q * 16;
    int lrow = flat >> 11;
    int off = flat & 2047;
    int dst = flat ^ ((lrow & 7) << 4);
    const ushort_t* src;
    if (lrow < 16)      src = WhhH + (size_t)(c0 + lrow) * HDIM;
    else if (lrow < 32) src = WhhH + (size_t)(1024 + c0 + lrow - 16) * HDIM;
    else if (lrow < 48) src = WhhH + (size_t)(2048 + c0 + lrow - 32) * HDIM;
    else                src = WhhL + (size_t)(2048 + c0 + lrow - 48) * HDIM;
    *(sh8*)(lds + dst) = *(const sh8*)(src + (off >> 1));
  }
  __syncthreads();

  const float br = bias_hh[c], bz = bias_hh[1024 + c], bn = bias_hh[2048 + c];
  unsigned bar = 0;

  // own-column h carried exactly in fp32 registers across the whole sequence
  float hold[4];
  #pragma unroll
  for (int j = 0; j < 4; ++j) hold[j] = h0f[(m0 + rb + j) * HDIM + c];

  // prefetch gx r,z,n for t=0
  float gxr[4], gxz[4], gxn[4];
  #pragma unroll
  for (int j = 0; j < 4; ++j) {
    int b = m0 + rb + j;
    gxr[j] = __builtin_nontemporal_load(gx + (size_t)b * G3 + c);
    gxz[j] = __builtin_nontemporal_load(gx + (size_t)b * G3 + 1024 + c);
    gxn[j] = __builtin_nontemporal_load(gx + (size_t)b * G3 + 2048 + c);
  }

  for (int t = 0; t < SEQL; ++t) {
    const int par = t & 1;

    // ---- stage 1: full-burst h load, then r,z GEMM (h hi-only) ----
    const ushort_t* ha = hH + par * BH + (size_t)(m0 + lr) * HDIM + lk;
    sh8 bufa[32];
    #pragma unroll
    for (int i = 0; i < 32; ++i) bufa[i] = *(const sh8*)(ha + i * 32);

    f32x4 accR = (f32x4){0,0,0,0}, accZ = (f32x4){0,0,0,0};
    #pragma unroll
    for (int i = 0; i < 32; ++i) {
      int byt = ((lr << 11) + ((i * 32 + lk) << 1)) ^ ((lr & 7) << 4);
      sh8 rW = *(const sh8*)(lds + byt);
      sh8 zW = *(const sh8*)(lds + 32768 + byt);
      accR = MFMA16(bufa[i], rW, accR);
      accZ = MFMA16(bufa[i], zW, accZ);
    }

    float zreg[4];
    #pragma unroll
    for (int j = 0; j < 4; ++j) {
      int b = m0 + rb + j;
      float pr = accR[j] + gxr[j] + br;
      float pz = accZ[j] + gxz[j] + bz;
      float r = 1.f / (1.f + __expf(-pr));
      zreg[j] = 1.f / (1.f + __expf(-pz));
      rhH[b * HDIM + c] = f2bf(r * hold[j]);      // normal store (stays cached)
    }
    ++bar;
    gbar_flat(slots, g, tid, bar);

    // ---- stage 2: full-burst rh load; prefetch gx[t+1]; n GEMM (rh hi-only) ----
    const ushort_t* ra = rhH + (size_t)(m0 + lr) * HDIM + lk;
    #pragma unroll
    for (int i = 0; i < 32; ++i) bufa[i] = *(const sh8*)(ra + i * 32);

    {
      int tn = (t + 1 < SEQL) ? t + 1 : t;
      const float* gxn2 = gx + (size_t)tn * (BATCH * G3);
      #pragma unroll
      for (int j = 0; j < 4; ++j) {
        int b = m0 + rb + j;
        gxr[j] = __builtin_nontemporal_load(gxn2 + (size_t)b * G3 + c);
        gxz[j] = __builtin_nontemporal_load(gxn2 + (size_t)b * G3 + 1024 + c);
      }
    }

    f32x4 accN = (f32x4){0,0,0,0};
    #pragma unroll
    for (int i = 0; i < 32; ++i) {
      int byt = ((lr << 11) + ((i * 32 + lk) << 1)) ^ ((lr & 7) << 4);
      sh8 nW = *(const sh8*)(lds + 65536 + byt);
      sh8 nLo = *(const sh8*)(lds + 98304 + byt);
      accN = MFMA16(bufa[i], nW, accN);
      accN = MFMA16(bufa[i], nLo, accN);
    }

    ushort_t* hHn = hH + (par ^ 1) * BH;
    float gxnN[4];
    {
      int tn = (t + 1 < SEQL) ? t + 1 : t;
      const float* gxn2 = gx + (size_t)tn * (BATCH * G3);
      #pragma unroll
      for (int j = 0; j < 4; ++j) {
        int b = m0 + rb + j;
        gxnN[j] = __builtin_nontemporal_load(gxn2 + (size_t)b * G3 + 2048 + c);
      }
    }
    #pragma unroll
    for (int j = 0; j < 4; ++j) {
      int b = m0 + rb + j;
      float pn = accN[j] + gxn[j] + bn;
      float n = tanhf(pn);
      float z = zreg[j];
      float hnew = (1.f - z) * n + z * hold[j];
      hold[j] = hnew;
      __builtin_nontemporal_store(hnew, &Y[(size_t)t * BH + b * HDIM + c]);
      hHn[b * HDIM + c] = f2bf(hnew);             // normal store (stays cached)
      if (t == SEQL - 1) __builtin_nontemporal_store(hnew, &Yh[b * HDIM + c]);
    }
    #pragma unroll
    for (int j = 0; j < 4; ++j) gxn[j] = gxnN[j];

    if (t < SEQL - 1) {
      ++bar;
      gbar_flat(slots, g, tid, bar);
    }
  }
}

// ---------------- launch ----------------
extern "C" void kernel_launch(void* const* d_in, const int* in_sizes, int n_in,
                              void* d_out, int out_size, void* d_ws, size_t ws_size,
                              hipStream_t stream) {
  const float* input = (const float*)d_in[0];
  const float* h0    = (const float*)d_in[1];
  const float* wih   = (const float*)d_in[2];
  const float* whh   = (const float*)d_in[3];
  const float* bih   = (const float*)d_in[4];
  const float* bhh   = (const float*)d_in[5];

  char* ws = (char*)d_ws;
  size_t o = 0;
  float* gx = (float*)(ws + o);         o += (size_t)AROWS * G3 * 4;
  ushort_t* WihH = (ushort_t*)(ws + o); o += (size_t)G3 * HDIM * 2;
  ushort_t* WihL = (ushort_t*)(ws + o); o += (size_t)G3 * HDIM * 2;
  ushort_t* WhhH = (ushort_t*)(ws + o); o += (size_t)G3 * HDIM * 2;
  ushort_t* WhhL = (ushort_t*)(ws + o); o += (size_t)G3 * HDIM * 2;
  ushort_t* hH = (ushort_t*)(ws + o);   o += 2 * (size_t)BH * 2;
  ushort_t* rhH = (ushort_t*)(ws + o);  o += (size_t)BH * 2;
  unsigned* slots = (unsigned*)(ws + o); o += (size_t)NWG * 128;

  float* Y  = (float*)d_out;
  float* Yh = (float*)d_out + (size_t)YSZ;

  (void)hipFuncSetAttribute((const void*)gru_rec,
                            hipFuncAttributeMaxDynamicSharedMemorySize, 131072);

  (void)hipMemsetAsync(slots, 0, (size_t)NWG * 128, stream);
  cvt_kernel<<<2048, 256, 0, stream>>>(wih, whh, h0, WihH, WihL, WhhH, WhhL, hH);
  gemm_gx<<<(AROWS / 128) * (G3 / 128), 256, 0, stream>>>(input, WihH, WihL, bih, gx);
  gru_rec<<<64, 256, 131072, stream>>>(gx, WhhH, WhhL, bhh, h0, hH, rhH, Y, Yh, slots);
}